// Round 12
// baseline (371.424 us; speedup 1.0000x reference)
//
#include <hip/hip_runtime.h>
#include <hip/hip_bf16.h>

typedef float  f32x4 __attribute__((ext_vector_type(4)));
typedef short  s16x8 __attribute__((ext_vector_type(8)));

#define MEMH   256        // mem_dim
#define MSGD   512        // msg_dim
#define G3     768        // 3*H
#define W_IH_ELEMS (G3*MSGD)        // 393216
#define W_HH_ELEMS (G3*MEMH)        // 196608
#define W_TOT_ELEMS (W_IH_ELEMS + W_HH_ELEMS)  // 589824
#define W_BYTES    ((size_t)W_TOT_ELEMS * 2)   // 1179648

#define BM      32        // rows per GRU block
#define NTHR    1024      // 16 waves, each owns gate-triple {w, 16+w, 32+w}
#define AM_OFF  0         // msg bf16 32x512, pitch 1024 B, XOR swz -> 32768
#define AH_OFF  32768     // A_h bf16 32x256, pitch 512 B, XOR swz -> 16384
#define B_OFF   49152     // per-wave B dbuf: 16 waves x 2 bufs x 3 KB -> 98304
#define PART_OFF 147456   // part[32][16][2] f32 -> 4096
#define LDS_BYTES 151552

typedef const __attribute__((address_space(1))) void* gas_p;
typedef __attribute__((address_space(3)))       void* las_p;

static __device__ __forceinline__ short f2bf(float x) {
    __hip_bfloat16 b = __float2bfloat16(x);
    return __builtin_bit_cast(short, b);
}
static __device__ __forceinline__ float bf2f(short s) {
    unsigned int u = ((unsigned int)(unsigned short)s) << 16;
    return __builtin_bit_cast(float, u);
}
static __device__ __forceinline__ s16x8 cvt8(f32x4 a, f32x4 b) {
    s16x8 s;
    s[0]=f2bf(a[0]); s[1]=f2bf(a[1]); s[2]=f2bf(a[2]); s[3]=f2bf(a[3]);
    s[4]=f2bf(b[0]); s[5]=f2bf(b[1]); s[6]=f2bf(b[2]); s[7]=f2bf(b[3]);
    return s;
}
static __device__ __forceinline__ float sigf(float x) {
    return 1.f / (1.f + __expf(-x));
}
static __device__ __forceinline__ float tanh_fast(float x) {
    float e = __expf(-2.f * fabsf(x));
    float t = (1.f - e) / (1.f + e);
    return copysignf(t, x);
}
static __device__ __forceinline__ f32x4 ntload4(const float* p) {
    return __builtin_nontemporal_load((const f32x4*)p);
}
static __device__ __forceinline__ void ntstore4(float* p, f32x4 v) {
    __builtin_nontemporal_store(v, (f32x4*)p);
}

// ------------------------------------------------- full copy kernel (fallback)
__global__ void smu_copy_kernel(const float* __restrict__ mem,
                                const float* __restrict__ lu,
                                float* __restrict__ out_mem,
                                float* __restrict__ out_lu,
                                long n_mem4, long n_lu4) {
    long i = (long)blockIdx.x * blockDim.x + threadIdx.x;
    long stride = (long)gridDim.x * blockDim.x;
    long total = n_mem4 + n_lu4;
    for (; i < total; i += stride) {
        if (i < n_mem4) ntstore4(out_mem + i * 4, ntload4(mem + i * 4));
        else {
            long j = (i - n_mem4) * 4;
            ntstore4(out_lu + j, ntload4(lu + j));
        }
    }
}

// ---------------------------------------- bitmap-skip copy (measured ~6 TB/s)
__global__ __launch_bounds__(256)
void smu_copy_skip_kernel(const float* __restrict__ mem,
                          const float* __restrict__ lu,
                          const unsigned* __restrict__ bm,
                          float* __restrict__ out_mem,
                          float* __restrict__ out_lu,
                          long n_nodes) {
    const long nu = n_nodes * (MEMH / 4);                 // 16B units
    const long stride = (long)gridDim.x * blockDim.x;
    const long i0 = (long)blockIdx.x * blockDim.x + threadIdx.x;

    for (long i = i0; i < nu; i += stride) {
        long r = i >> 6;
        if (!((bm[r >> 5] >> (r & 31)) & 1u))
            ntstore4(out_mem + i * 4, ntload4(mem + i * 4));
    }
    for (long i = i0; i < n_nodes; i += stride) {
        if (!((bm[i >> 5] >> (i & 31)) & 1u)) {
            float v = __builtin_nontemporal_load(lu + i);
            __builtin_nontemporal_store(v, out_lu + i);
        }
    }
}

// --------------------------------------------------- weight fp32->bf16 PACKED fragment layout
// ih: frag (t in [0,48), k in [0,16)) at elem off (t*16+k)*512; within frag
// elem idx = l*8+e  ->  source row t*16+(l&15), col k*32+(l>>4)*8+e.
// hh: frag (t in [0,48), k in [0,8)) at W_IH_ELEMS + (t*8+k)*512, same inner map.
__global__ void smu_cvtw_kernel(const float* __restrict__ wih,
                                const float* __restrict__ whh,
                                short* __restrict__ o) {
    int i = blockIdx.x * blockDim.x + threadIdx.x;
    if (i >= W_TOT_ELEMS) return;
    if (i < W_IH_ELEMS) {
        int f = i >> 9, r = i & 511, l = r >> 3, e = r & 7;
        int t = f >> 4, k = f & 15;
        int row = t * 16 + (l & 15), col = k * 32 + (l >> 4) * 8 + e;
        o[i] = f2bf(wih[row * MSGD + col]);
    } else {
        int j = i - W_IH_ELEMS;
        int f = j >> 9, r = j & 511, l = r >> 3, e = r & 7;
        int t = f >> 3, k = f & 7;
        int row = t * 16 + (l & 15), col = k * 32 + (l >> 4) * 8 + e;
        o[i] = f2bf(whh[row * MEMH + col]);
    }
}

// --------------------------------------------------- bitmap clear + set
__global__ void smu_clear_kernel(unsigned* __restrict__ p, int n) {
    int i = blockIdx.x * blockDim.x + threadIdx.x;
    if (i < n) p[i] = 0u;
}
__global__ void smu_bits_kernel(const int* __restrict__ ids,
                                unsigned* __restrict__ bm, int n) {
    int i = blockIdx.x * blockDim.x + threadIdx.x;
    if (i < n) {
        int id = ids[i];
        atomicOr(&bm[id >> 5], 1u << (id & 31));
    }
}

// --------------------------------------------------------------- GRU kernel (DMA weights)
// 1024 threads (16 waves), BM=32. Wave w owns gate-triple tiles {w, 16+w, 32+w}
// -> lane column j = w*16 + (lane&15); gate math lane-local. m = 2 row-tiles.
// Weights: per k-step each wave DMAs its own 3 x 1KB fragments from the packed
// bf16 workspace into a PRIVATE double-buffered LDS slot via
// __builtin_amdgcn_global_load_lds (wave-uniform dest + lane*16), consumed
// after a counted s_waitcnt vmcnt(3). Wave-local producer/consumer: NO barriers
// in the k-loop, no B-load->register->MFMA dependency chain.
__global__ __launch_bounds__(NTHR, 1)
void smu_gru_dma_kernel(const int*   __restrict__ ids,
                        const float* __restrict__ msg,
                        const float* __restrict__ ts,
                        const float* __restrict__ memory,
                        const float* __restrict__ b_ih,
                        const float* __restrict__ b_hh,
                        const float* __restrict__ gamma,
                        const float* __restrict__ beta,
                        const short* __restrict__ wsw,
                        float* __restrict__ out_mem,
                        float* __restrict__ out_lu) {
    __shared__ __align__(16) unsigned char lds[LDS_BYTES];
    const int tid = threadIdx.x;
    const long base = (long)blockIdx.x * BM;

    const int lane = tid & 63;
    const int w    = tid >> 6;              // 0..15
    const int lr   = lane & 15;
    const int lq   = lane >> 4;             // 0..3
    const int lk8  = lq * 8;
    const int sw   = (lr & 7) << 4;
    const short* Wi = wsw;
    const short* Wh = wsw + W_IH_ELEMS;

    // ---- stage A_msg: 32x512 (2048 units, 2/thread) + A_h gather (1024 units, 1/thread)
    {
        const float* src = msg + base * MSGD;
        #pragma unroll
        for (int it = 0; it < 2; ++it) {
            int u = tid + NTHR * it;         // 0..2047, 64 units/row
            int row = u >> 6;
            f32x4 a = ntload4(src + u * 8);
            f32x4 b = ntload4(src + u * 8 + 4);
            int byte = AM_OFF + ((u * 16) ^ ((row & 7) << 4));
            *(s16x8*)(lds + byte) = cvt8(a, b);
        }
        {
            int u = tid;                     // 0..1023, 32 units/row
            int row = u >> 5;
            int c8  = u & 31;
            int id  = ids[base + row];
            const float* hs = memory + (size_t)id * MEMH + c8 * 8;
            f32x4 a = ntload4(hs);
            f32x4 b = ntload4(hs + 4);
            int byte = AH_OFF + ((u * 16) ^ ((row & 7) << 4));
            *(s16x8*)(lds + byte) = cvt8(a, b);
        }
    }
    __syncthreads();   // drains staging vmem/lds -> vmcnt baseline 0 for the DMA pipe

    const int bbase = B_OFF + w * 6144;      // this wave's 2x3KB B area
    f32x4 rz[2][2] = {};    // [m][0]=r-sum [1]=z-sum (both GEMMs accumulate)
    f32x4 gin[2]   = {};    // gi_n
    f32x4 ghn[2]   = {};    // gh_n

    // ---- GEMM 1: msg @ W_ih^T, K=512, 16 k-steps, per-wave DMA dbuf
    {
        #pragma unroll
        for (int g = 0; g < 3; ++g)
            __builtin_amdgcn_global_load_lds(
                (gas_p)(const void*)(Wi + (((16 * g + w) * 16 + 0) << 9) + lane * 8),
                (las_p)(void*)(lds + bbase + g * 1024), 16, 0, 0);
        #pragma unroll
        for (int k = 0; k < 16; ++k) {
            if (k < 15) {
                const int nb = bbase + ((k + 1) & 1) * 3072;
                #pragma unroll
                for (int g = 0; g < 3; ++g)
                    __builtin_amdgcn_global_load_lds(
                        (gas_p)(const void*)(Wi + (((16 * g + w) * 16 + (k + 1)) << 9) + lane * 8),
                        (las_p)(void*)(lds + nb + g * 1024), 16, 0, 0);
                asm volatile("s_waitcnt vmcnt(3)" ::: "memory");
            } else {
                asm volatile("s_waitcnt vmcnt(0)" ::: "memory");
            }
            const int bufo = bbase + (k & 1) * 3072;
            s16x8 b0 = *(const s16x8*)(lds + bufo + 0 * 1024 + lane * 16);
            s16x8 b1 = *(const s16x8*)(lds + bufo + 1 * 1024 + lane * 16);
            s16x8 b2 = *(const s16x8*)(lds + bufo + 2 * 1024 + lane * 16);
            const int cb = (k * 32 + lk8) * 2;
            #pragma unroll
            for (int m = 0; m < 2; ++m) {
                s16x8 a = *(const s16x8*)(lds + AM_OFF + (((m*16 + lr) * 1024 + cb) ^ sw));
                rz[m][0] = __builtin_amdgcn_mfma_f32_16x16x32_bf16(a, b0, rz[m][0], 0, 0, 0);
                rz[m][1] = __builtin_amdgcn_mfma_f32_16x16x32_bf16(a, b1, rz[m][1], 0, 0, 0);
                gin[m]   = __builtin_amdgcn_mfma_f32_16x16x32_bf16(a, b2, gin[m],   0, 0, 0);
            }
        }
    }
    // ---- GEMM 2: h @ W_hh^T, K=256, 8 k-steps (A_h written pre-GEMM1 barrier)
    {
        #pragma unroll
        for (int g = 0; g < 3; ++g)
            __builtin_amdgcn_global_load_lds(
                (gas_p)(const void*)(Wh + (((16 * g + w) * 8 + 0) << 9) + lane * 8),
                (las_p)(void*)(lds + bbase + g * 1024), 16, 0, 0);
        #pragma unroll
        for (int k = 0; k < 8; ++k) {
            if (k < 7) {
                const int nb = bbase + ((k + 1) & 1) * 3072;
                #pragma unroll
                for (int g = 0; g < 3; ++g)
                    __builtin_amdgcn_global_load_lds(
                        (gas_p)(const void*)(Wh + (((16 * g + w) * 8 + (k + 1)) << 9) + lane * 8),
                        (las_p)(void*)(lds + nb + g * 1024), 16, 0, 0);
                asm volatile("s_waitcnt vmcnt(3)" ::: "memory");
            } else {
                asm volatile("s_waitcnt vmcnt(0)" ::: "memory");
            }
            const int bufo = bbase + (k & 1) * 3072;
            s16x8 b0 = *(const s16x8*)(lds + bufo + 0 * 1024 + lane * 16);
            s16x8 b1 = *(const s16x8*)(lds + bufo + 1 * 1024 + lane * 16);
            s16x8 b2 = *(const s16x8*)(lds + bufo + 2 * 1024 + lane * 16);
            const int cb = (k * 32 + lk8) * 2;
            #pragma unroll
            for (int m = 0; m < 2; ++m) {
                s16x8 a = *(const s16x8*)(lds + AH_OFF + (((m*16 + lr) * 512 + cb) ^ sw));
                rz[m][0] = __builtin_amdgcn_mfma_f32_16x16x32_bf16(a, b0, rz[m][0], 0, 0, 0);
                rz[m][1] = __builtin_amdgcn_mfma_f32_16x16x32_bf16(a, b1, rz[m][1], 0, 0, 0);
                ghn[m]   = __builtin_amdgcn_mfma_f32_16x16x32_bf16(a, b2, ghn[m],   0, 0, 0);
            }
        }
    }

    // ---- gate epilogue in registers (A_h LDS intact). Lane column j.
    const int j = w * 16 + lr;               // 0..255
    f32x4 o_[2];
    {
        const float br = b_ih[j]       + b_hh[j];
        const float bz = b_ih[256 + j] + b_hh[256 + j];
        const float bihn = b_ih[512 + j], bhhn = b_hh[512 + j];
        #pragma unroll
        for (int m = 0; m < 2; ++m) {
            #pragma unroll
            for (int q = 0; q < 4; ++q) {
                int row = m * 16 + lq * 4 + q;
                float r = sigf(rz[m][0][q] + br);
                float z = sigf(rz[m][1][q] + bz);
                float n = tanh_fast(gin[m][q] + bihn + r * (ghn[m][q] + bhhn));
                float hv = bf2f(*(const short*)(lds + AH_OFF + ((row * 512 + j * 2) ^ ((row & 7) << 4))));
                o_[m][q] = (1.f - z) * n + z * hv;
            }
        }
    }

    // ---- per-wave LN partials (16 cols per wave per row)
    {
        float* part = (float*)(lds + PART_OFF);
        #pragma unroll
        for (int m = 0; m < 2; ++m) {
            #pragma unroll
            for (int q = 0; q < 4; ++q) {
                float v = o_[m][q];
                float s1 = v, s2 = v * v;
                #pragma unroll
                for (int mk = 1; mk < 16; mk <<= 1) {
                    s1 += __shfl_xor(s1, mk);
                    s2 += __shfl_xor(s2, mk);
                }
                if (lr == 0) {
                    int row = m * 16 + lq * 4 + q;
                    part[(row * 16 + w) * 2]     = s1;
                    part[(row * 16 + w) * 2 + 1] = s2;
                }
            }
        }
    }
    __syncthreads();

    // ---- per-lane row stats (redundant; broadcast LDS reads)
    float mu_[2][4], inv_[2][4];
    {
        const float* part = (const float*)(lds + PART_OFF);
        #pragma unroll
        for (int m = 0; m < 2; ++m) {
            #pragma unroll
            for (int q = 0; q < 4; ++q) {
                int row = m * 16 + lq * 4 + q;
                float s1 = 0.f, s2 = 0.f;
                #pragma unroll
                for (int i = 0; i < 16; ++i) {
                    s1 += part[(row * 16 + i) * 2];
                    s2 += part[(row * 16 + i) * 2 + 1];
                }
                float mu  = s1 * (1.f / 256.f);
                float var = fmaxf(s2 * (1.f / 256.f) - mu * mu, 0.f);
                mu_[m][q]  = mu;
                inv_[m][q] = rsqrtf(var + 1e-5f);
            }
        }
    }

    // ---- normalize + scatter
    {
        const float ga = gamma[j], be = beta[j];
        #pragma unroll
        for (int m = 0; m < 2; ++m) {
            #pragma unroll
            for (int q = 0; q < 4; ++q) {
                int row = m * 16 + lq * 4 + q;
                int id = ids[base + row];
                float y = (o_[m][q] - mu_[m][q]) * inv_[m][q] * ga + be;
                __builtin_nontemporal_store(y, out_mem + (size_t)id * MEMH + j);
            }
        }
        if (w == 0 && lane < 32) {
            int id = ids[base + lane];
            __builtin_nontemporal_store(ts[base + lane], out_lu + id);
        }
    }
}

// --------------------------------------------------------------- GRU fallback (no workspace)
__global__ __launch_bounds__(512, 4)
void smu_gru_fb_kernel(const int*   __restrict__ ids,
                       const float* __restrict__ msg,
                       const float* __restrict__ ts,
                       const float* __restrict__ memory,
                       const float* __restrict__ W_ih,
                       const float* __restrict__ W_hh,
                       const float* __restrict__ b_ih,
                       const float* __restrict__ b_hh,
                       const float* __restrict__ gamma,
                       const float* __restrict__ beta,
                       float* __restrict__ out_mem,
                       float* __restrict__ out_lu) {
    __shared__ __align__(16) unsigned char lds[51200];
    const int tid = threadIdx.x;
    const long base = (long)blockIdx.x * 32;

    {
        const float* src = msg + base * MSGD;
        #pragma unroll
        for (int it = 0; it < 4; ++it) {
            int u = tid + 512 * it;
            int row = u >> 6;
            f32x4 a = ntload4(src + u * 8);
            f32x4 b = ntload4(src + u * 8 + 4);
            int byte = ((u * 16) ^ ((row & 7) << 4));
            *(s16x8*)(lds + byte) = cvt8(a, b);
        }
        #pragma unroll
        for (int it = 0; it < 2; ++it) {
            int u = tid + 512 * it;
            int row = u >> 5;
            int c8  = u & 31;
            int id  = ids[base + row];
            const float* hs = memory + (size_t)id * MEMH + c8 * 8;
            f32x4 a = ntload4(hs);
            f32x4 b = ntload4(hs + 4);
            int byte = 32768 + ((u * 16) ^ ((row & 7) << 4));
            *(s16x8*)(lds + byte) = cvt8(a, b);
        }
    }
    __syncthreads();

    const int lane = tid & 63;
    const int w    = tid >> 6;
    const int lr   = lane & 15;
    const int lq   = lane >> 4;
    const int lk8  = lq * 8;
    const int sw   = (lr & 7) << 4;

    auto loadb = [&](const float* Wf, int t, int k, int ldk) {
        int row = t * 16 + lr;
        int col = k * 32 + lk8;
        f32x4 x = *(const f32x4*)(Wf + (size_t)row * ldk + col);
        f32x4 y = *(const f32x4*)(Wf + (size_t)row * ldk + col + 4);
        return cvt8(x, y);
    };

    f32x4 rz[2][2][2] = {};
    f32x4 gin[2][2]   = {};
    f32x4 ghn[2][2]   = {};

    for (int k = 0; k < 16; ++k) {
        const int cb = (k * 32 + lk8) * 2;
        #pragma unroll
        for (int m = 0; m < 2; ++m) {
            s16x8 a = *(const s16x8*)(lds + (((m*16 + lr) * 1024 + cb) ^ sw));
            #pragma unroll
            for (int ci = 0; ci < 2; ++ci) {
                s16x8 b0 = loadb(W_ih, w + 8*ci + 0,  k, MSGD);
                s16x8 b1 = loadb(W_ih, w + 8*ci + 16, k, MSGD);
                s16x8 b2 = loadb(W_ih, w + 8*ci + 32, k, MSGD);
                rz[m][ci][0] = __builtin_amdgcn_mfma_f32_16x16x32_bf16(a, b0, rz[m][ci][0], 0, 0, 0);
                rz[m][ci][1] = __builtin_amdgcn_mfma_f32_16x16x32_bf16(a, b1, rz[m][ci][1], 0, 0, 0);
                gin[m][ci]   = __builtin_amdgcn_mfma_f32_16x16x32_bf16(a, b2, gin[m][ci],   0, 0, 0);
            }
        }
    }
    for (int k = 0; k < 8; ++k) {
        const int cb = (k * 32 + lk8) * 2;
        #pragma unroll
        for (int m = 0; m < 2; ++m) {
            s16x8 a = *(const s16x8*)(lds + 32768 + (((m*16 + lr) * 512 + cb) ^ sw));
            #pragma unroll
            for (int ci = 0; ci < 2; ++ci) {
                s16x8 b0 = loadb(W_hh, w + 8*ci + 0,  k, MEMH);
                s16x8 b1 = loadb(W_hh, w + 8*ci + 16, k, MEMH);
                s16x8 b2 = loadb(W_hh, w + 8*ci + 32, k, MEMH);
                rz[m][ci][0] = __builtin_amdgcn_mfma_f32_16x16x32_bf16(a, b0, rz[m][ci][0], 0, 0, 0);
                rz[m][ci][1] = __builtin_amdgcn_mfma_f32_16x16x32_bf16(a, b1, rz[m][ci][1], 0, 0, 0);
                ghn[m][ci]   = __builtin_amdgcn_mfma_f32_16x16x32_bf16(a, b2, ghn[m][ci],   0, 0, 0);
            }
        }
    }

    f32x4 o_[2][2];
    #pragma unroll
    for (int ci = 0; ci < 2; ++ci) {
        const int j = (w + 8*ci) * 16 + lr;
        const float br = b_ih[j]       + b_hh[j];
        const float bz = b_ih[256 + j] + b_hh[256 + j];
        const float bihn = b_ih[512 + j], bhhn = b_hh[512 + j];
        #pragma unroll
        for (int m = 0; m < 2; ++m) {
            #pragma unroll
            for (int q = 0; q < 4; ++q) {
                int row = m * 16 + lq * 4 + q;
                float r = sigf(rz[m][ci][0][q] + br);
                float z = sigf(rz[m][ci][1][q] + bz);
                float n = tanh_fast(gin[m][ci][q] + bihn + r * (ghn[m][ci][q] + bhhn));
                float hv = bf2f(*(const short*)(lds + 32768 + ((row * 512 + j * 2) ^ ((row & 7) << 4))));
                o_[m][ci][q] = (1.f - z) * n + z * hv;
            }
        }
    }

    float* part = (float*)(lds + 49152);
    #pragma unroll
    for (int m = 0; m < 2; ++m)
        #pragma unroll
        for (int q = 0; q < 4; ++q) {
            float v0 = o_[m][0][q], v1 = o_[m][1][q];
            float s1 = v0 + v1, s2 = v0*v0 + v1*v1;
            #pragma unroll
            for (int mk = 1; mk < 16; mk <<= 1) {
                s1 += __shfl_xor(s1, mk);
                s2 += __shfl_xor(s2, mk);
            }
            if (lr == 0) {
                int row = m * 16 + lq * 4 + q;
                part[(row * 8 + w) * 2]     = s1;
                part[(row * 8 + w) * 2 + 1] = s2;
            }
        }
    __syncthreads();

    #pragma unroll
    for (int ci = 0; ci < 2; ++ci) {
        const int j = (w + 8*ci) * 16 + lr;
        const float ga = gamma[j], be = beta[j];
        #pragma unroll
        for (int m = 0; m < 2; ++m)
            #pragma unroll
            for (int q = 0; q < 4; ++q) {
                int row = m * 16 + lq * 4 + q;
                float s1 = 0.f, s2 = 0.f;
                #pragma unroll
                for (int i = 0; i < 8; ++i) {
                    s1 += part[(row * 8 + i) * 2];
                    s2 += part[(row * 8 + i) * 2 + 1];
                }
                float mu  = s1 * (1.f / 256.f);
                float var = fmaxf(s2 * (1.f / 256.f) - mu * mu, 0.f);
                float inv = rsqrtf(var + 1e-5f);
                int id = ids[base + row];
                float y = (o_[m][ci][q] - mu) * inv * ga + be;
                __builtin_nontemporal_store(y, out_mem + (size_t)id * MEMH + j);
            }
    }
    if (w == 0 && lane < 32) {
        int id = ids[base + lane];
        __builtin_nontemporal_store(ts[base + lane], out_lu + id);
    }
}

// ------------------------------------------------------------------- launcher
extern "C" void kernel_launch(void* const* d_in, const int* in_sizes, int n_in,
                              void* d_out, int out_size, void* d_ws, size_t ws_size,
                              hipStream_t stream) {
    (void)n_in; (void)out_size;
    const int*   ids = (const int*)  d_in[0];
    const float* msg = (const float*)d_in[1];
    const float* ts  = (const float*)d_in[2];
    const float* mem = (const float*)d_in[3];
    const float* lu  = (const float*)d_in[4];
    const float* Wih = (const float*)d_in[5];
    const float* Whh = (const float*)d_in[6];
    const float* bih = (const float*)d_in[7];
    const float* bhh = (const float*)d_in[8];
    const float* gam = (const float*)d_in[9];
    const float* bet = (const float*)d_in[10];

    const int  n_upd   = in_sizes[0];                 // 65536
    const long n_nodes = (long)in_sizes[3] / MEMH;    // 500000

    float* out_mem = (float*)d_out;
    float* out_lu  = out_mem + (size_t)n_nodes * MEMH;

    const int    bm_words     = (int)((n_nodes + 31) / 32) + 4;   // padded
    const size_t bm_bytes_pad = (size_t)bm_words * 4;
    const bool ws_ok = (d_ws != nullptr) && (ws_size >= W_BYTES + bm_bytes_pad);

    short*    wsw = (short*)d_ws;
    unsigned* bm  = (unsigned*)((char*)d_ws + W_BYTES);

    if (ws_ok) {
        // clear -> bits -> copy (bitmap-skipped) -> cvtw (weights L2-hot) -> gru(DMA)
        smu_clear_kernel<<<(bm_words + 255) / 256, 256, 0, stream>>>(bm, bm_words);
        smu_bits_kernel<<<(n_upd + 255) / 256, 256, 0, stream>>>(ids, bm, n_upd);
        smu_copy_skip_kernel<<<2048, 256, 0, stream>>>(mem, lu, bm, out_mem, out_lu, n_nodes);
        smu_cvtw_kernel<<<(W_TOT_ELEMS + 255) / 256, 256, 0, stream>>>(Wih, Whh, wsw);
        smu_gru_dma_kernel<<<n_upd / BM, NTHR, 0, stream>>>(
            ids, msg, ts, mem, bih, bhh, gam, bet, wsw, out_mem, out_lu);
    } else {
        // fallback: full copy first, then GRU scatter overwrites updated rows
        long n_mem4 = n_nodes * (MEMH / 4);
        long n_lu4  = n_nodes / 4;
        smu_copy_kernel<<<2048, 256, 0, stream>>>(mem, lu, out_mem, out_lu, n_mem4, n_lu4);
        smu_gru_fb_kernel<<<n_upd / 32, 512, 0, stream>>>(
            ids, msg, ts, mem, Wih, Whh, bih, bhh, gam, bet, out_mem, out_lu);
    }
}

// Round 13
// 339.048 us; speedup vs baseline: 1.0955x; 1.0955x over previous
//
#include <hip/hip_runtime.h>
#include <hip/hip_bf16.h>

typedef float  f32x4 __attribute__((ext_vector_type(4)));
typedef short  s16x8 __attribute__((ext_vector_type(8)));

#define MEMH   256        // mem_dim
#define MSGD   512        // msg_dim
#define G3     768        // 3*H
#define W_IH_ELEMS (G3*MSGD)        // 393216
#define W_HH_ELEMS (G3*MEMH)        // 196608
#define W_TOT_ELEMS (W_IH_ELEMS + W_HH_ELEMS)  // 589824
#define W_BYTES    ((size_t)W_TOT_ELEMS * 2)   // 1179648

#define BM     64         // rows per GRU block
#define NTHR   1024       // 16 waves
#define AM_OFF 0          // A_msg: 64x512 bf16, pitch 1024 B -> 65536 B
#define AH_OFF 65536      // A_h:   64x256 bf16, pitch 512 B  -> 32768 B
#define PART_OFF 98304    // part[64][16][2] f32 -> 8192 B
#define STAT_OFF 106496   // stat[64][2] f32 -> 512 B
#define LDS_BYTES 107008

static __device__ __forceinline__ short f2bf(float x) {
    __hip_bfloat16 b = __float2bfloat16(x);
    return __builtin_bit_cast(short, b);
}
static __device__ __forceinline__ float bf2f(short s) {
    unsigned int u = ((unsigned int)(unsigned short)s) << 16;
    return __builtin_bit_cast(float, u);
}
static __device__ __forceinline__ s16x8 cvt8(f32x4 a, f32x4 b) {
    s16x8 s;
    s[0]=f2bf(a[0]); s[1]=f2bf(a[1]); s[2]=f2bf(a[2]); s[3]=f2bf(a[3]);
    s[4]=f2bf(b[0]); s[5]=f2bf(b[1]); s[6]=f2bf(b[2]); s[7]=f2bf(b[3]);
    return s;
}
static __device__ __forceinline__ float sigf(float x) {
    return 1.f / (1.f + __expf(-x));
}
static __device__ __forceinline__ float tanh_fast(float x) {
    float e = __expf(-2.f * fabsf(x));
    float t = (1.f - e) / (1.f + e);
    return copysignf(t, x);
}
static __device__ __forceinline__ f32x4 ntload4(const float* p) {
    return __builtin_nontemporal_load((const f32x4*)p);
}
static __device__ __forceinline__ void ntstore4(float* p, f32x4 v) {
    __builtin_nontemporal_store(v, (f32x4*)p);
}

// ------------------------------------------------- full copy kernel (fallback)
__global__ void smu_copy_kernel(const float* __restrict__ mem,
                                const float* __restrict__ lu,
                                float* __restrict__ out_mem,
                                float* __restrict__ out_lu,
                                long n_mem4, long n_lu4) {
    long i = (long)blockIdx.x * blockDim.x + threadIdx.x;
    long stride = (long)gridDim.x * blockDim.x;
    long total = n_mem4 + n_lu4;
    for (; i < total; i += stride) {
        if (i < n_mem4) ntstore4(out_mem + i * 4, ntload4(mem + i * 4));
        else {
            long j = (i - n_mem4) * 4;
            ntstore4(out_lu + j, ntload4(lu + j));
        }
    }
}

// --------------------------------------------------- weight fp32->bf16 PACKED fragment layout
// ih: frag (t in [0,48), k in [0,16)) at elem off (t*16+k)*512; within frag
// elem idx = l*8+e  ->  source row t*16+(l&15), col k*32+(l>>4)*8+e.
// hh: frag (t in [0,48), k in [0,8)) at W_IH_ELEMS + (t*8+k)*512, same inner map.
__global__ void smu_cvtw_kernel(const float* __restrict__ wih,
                                const float* __restrict__ whh,
                                short* __restrict__ o) {
    int i = blockIdx.x * blockDim.x + threadIdx.x;
    if (i >= W_TOT_ELEMS) return;
    if (i < W_IH_ELEMS) {
        int f = i >> 9, r = i & 511, l = r >> 3, e = r & 7;
        int t = f >> 4, k = f & 15;
        int row = t * 16 + (l & 15), col = k * 32 + (l >> 4) * 8 + e;
        o[i] = f2bf(wih[row * MSGD + col]);
    } else {
        int j = i - W_IH_ELEMS;
        int f = j >> 9, r = j & 511, l = r >> 3, e = r & 7;
        int t = f >> 3, k = f & 7;
        int row = t * 16 + (l & 15), col = k * 32 + (l >> 4) * 8 + e;
        o[i] = f2bf(whh[row * MEMH + col]);
    }
}

// --------------------------------------------------- bitmap clear + set
__global__ void smu_clear_kernel(unsigned* __restrict__ p, int n) {
    int i = blockIdx.x * blockDim.x + threadIdx.x;
    if (i < n) p[i] = 0u;
}
__global__ void smu_bits_kernel(const int* __restrict__ ids,
                                unsigned* __restrict__ bm, int n) {
    int i = blockIdx.x * blockDim.x + threadIdx.x;
    if (i < n) {
        int id = ids[i];
        atomicOr(&bm[id >> 5], 1u << (id & 31));
    }
}

// ------------------------------------------------------------ B-frag loader
template<bool USE_WS>
static __device__ __forceinline__ s16x8 load_b(const float* __restrict__ Wf,
                                               const short* __restrict__ Wb,
                                               int t, int k, int ldk, int nkt, int lane) {
    if constexpr (USE_WS) {
        return *(const s16x8*)(Wb + ((size_t)(t * nkt + k) << 9) + lane * 8);
    } else {
        int row = t * 16 + (lane & 15);
        int col = k * 32 + (lane >> 4) * 8;
        f32x4 x = *(const f32x4*)(Wf + (size_t)row * ldk + col);
        f32x4 y = *(const f32x4*)(Wf + (size_t)row * ldk + col + 4);
        return cvt8(x, y);
    }
}

// --------------------------------------------------------------- fused kernel
// grid = 2*n_gru_blocks. Even blocks: GRU+LN (BM=64 rows). Odd blocks:
// bitmap-skipped copy. Whole-block role divergence; row ownership disjoint
// (bitmap) -> race-free. This is the round-7 structure (best measured,
// 326.8 us) with the GRU epilogue switched from the 66KB LDS O-buffer to
// registers + 8.7KB LN partials (two fewer barriers, ~128KB/block less LDS
// traffic).
template<bool USE_WS, bool FUSED>
__global__ __launch_bounds__(NTHR, 1)
void smu_fused_kernel(const int*   __restrict__ ids,
                      const float* __restrict__ msg,
                      const float* __restrict__ ts,
                      const float* __restrict__ memory,
                      const float* __restrict__ lu,
                      const float* __restrict__ W_ih,
                      const float* __restrict__ W_hh,
                      const float* __restrict__ b_ih,
                      const float* __restrict__ b_hh,
                      const float* __restrict__ gamma,
                      const float* __restrict__ beta,
                      const short* __restrict__ wsw,
                      const unsigned* __restrict__ bm,
                      float* __restrict__ out_mem,
                      float* __restrict__ out_lu,
                      long n_nodes) {
    __shared__ __align__(16) unsigned char lds[LDS_BYTES];
    const int tid = threadIdx.x;
    const int bid = blockIdx.x;

    if (FUSED && (bid & 1)) {
        // ================= COPY role =================
        const long nblk   = gridDim.x >> 1;
        const long cid    = bid >> 1;
        const long nu     = n_nodes * (MEMH / 4);           // 16B units
        const long stride = nblk * NTHR;
        const long i0     = cid * NTHR + tid;

        for (long i = i0; i < nu; i += stride * 4) {
            long  u0 = i, u1 = i + stride, u2 = i + stride * 2, u3 = i + stride * 3;
            f32x4 v0, v1, v2, v3;
            bool  f0 = false, f1 = false, f2 = false, f3 = false;
            {
                long r0 = u0 >> 6;
                f0 = !((bm[r0 >> 5] >> (r0 & 31)) & 1u);
                if (f0) v0 = ntload4(memory + u0 * 4);
            }
            if (u1 < nu) {
                long r1 = u1 >> 6;
                f1 = !((bm[r1 >> 5] >> (r1 & 31)) & 1u);
                if (f1) v1 = ntload4(memory + u1 * 4);
            }
            if (u2 < nu) {
                long r2 = u2 >> 6;
                f2 = !((bm[r2 >> 5] >> (r2 & 31)) & 1u);
                if (f2) v2 = ntload4(memory + u2 * 4);
            }
            if (u3 < nu) {
                long r3 = u3 >> 6;
                f3 = !((bm[r3 >> 5] >> (r3 & 31)) & 1u);
                if (f3) v3 = ntload4(memory + u3 * 4);
            }
            if (f0) ntstore4(out_mem + u0 * 4, v0);
            if (f1) ntstore4(out_mem + u1 * 4, v1);
            if (f2) ntstore4(out_mem + u2 * 4, v2);
            if (f3) ntstore4(out_mem + u3 * 4, v3);
        }
        // last_update: scalar, bitmap-guarded
        for (long i = i0; i < n_nodes; i += stride) {
            if (!((bm[i >> 5] >> (i & 31)) & 1u)) {
                float v = __builtin_nontemporal_load(lu + i);
                __builtin_nontemporal_store(v, out_lu + i);
            }
        }
        return;
    }

    // ================= GRU role =================
    const long base = (long)(FUSED ? (bid >> 1) : bid) * BM;

    // ---- stage A_msg: 64x512 f32 -> bf16 (4096 8-elem units, 4/thread)
    {
        const float* src = msg + base * MSGD;
        #pragma unroll
        for (int it = 0; it < 4; ++it) {
            int u = tid + NTHR * it;         // 0..4095
            int row = u >> 6;                // 64 units per row
            f32x4 a = ntload4(src + u * 8);
            f32x4 b = ntload4(src + u * 8 + 4);
            int byte = AM_OFF + ((u * 16) ^ ((row & 7) << 4));
            *(s16x8*)(lds + byte) = cvt8(a, b);
        }
        // ---- stage A_h (gather): 64x256 (2048 units, 2/thread)
        #pragma unroll
        for (int it = 0; it < 2; ++it) {
            int u = tid + NTHR * it;         // 0..2047
            int row = u >> 5;                // 32 units per row
            int c8  = u & 31;
            int id  = ids[base + row];
            const float* hs = memory + (size_t)id * MEMH + c8 * 8;
            f32x4 a = ntload4(hs);
            f32x4 b = ntload4(hs + 4);
            int byte = AH_OFF + ((u * 16) ^ ((row & 7) << 4));
            *(s16x8*)(lds + byte) = cvt8(a, b);
        }
    }
    __syncthreads();

    const int lane = tid & 63;
    const int w    = tid >> 6;              // 0..15
    const int lr   = lane & 15;
    const int lq   = lane >> 4;             // 0..3
    const int lk8  = lq * 8;
    const int sw   = (lr & 7) << 4;
    const short* Wi = wsw;
    const short* Wh = wsw + W_IH_ELEMS;

    f32x4 acc[4][3] = {};   // [m][0]=r-sum  [1]=z-sum  [2]=gi_n
    f32x4 accn[4]   = {};   // gh_n

    // ---- GEMM 1: gi += msg @ W_ih^T  (K=512, 16 ktiles, depth-2 B prefetch)
    {
        s16x8 b[2][3];
        #pragma unroll
        for (int i = 0; i < 3; ++i) b[0][i] = load_b<USE_WS>(W_ih, Wi, w + 16*i, 0, MSGD, 16, lane);
        #pragma unroll
        for (int i = 0; i < 3; ++i) b[1][i] = load_b<USE_WS>(W_ih, Wi, w + 16*i, 1, MSGD, 16, lane);
        #pragma unroll
        for (int k = 0; k < 16; ++k) {
            const int cb = (k * 32 + lk8) * 2;
            #pragma unroll
            for (int m = 0; m < 4; ++m) {
                s16x8 a = *(const s16x8*)(lds + AM_OFF + (((m*16 + lr) * 1024 + cb) ^ sw));
                #pragma unroll
                for (int i = 0; i < 3; ++i)
                    acc[m][i] = __builtin_amdgcn_mfma_f32_16x16x32_bf16(a, b[k & 1][i], acc[m][i], 0, 0, 0);
            }
            if (k < 14) {
                #pragma unroll
                for (int i = 0; i < 3; ++i)
                    b[k & 1][i] = load_b<USE_WS>(W_ih, Wi, w + 16*i, k + 2, MSGD, 16, lane);
            }
        }
    }
    // ---- GEMM 2: h @ W_hh^T  (K=256, 8 ktiles)
    {
        s16x8 b[2][3];
        #pragma unroll
        for (int i = 0; i < 3; ++i) b[0][i] = load_b<USE_WS>(W_hh, Wh, w + 16*i, 0, MEMH, 8, lane);
        #pragma unroll
        for (int i = 0; i < 3; ++i) b[1][i] = load_b<USE_WS>(W_hh, Wh, w + 16*i, 1, MEMH, 8, lane);
        #pragma unroll
        for (int k = 0; k < 8; ++k) {
            const int cb = (k * 32 + lk8) * 2;
            #pragma unroll
            for (int m = 0; m < 4; ++m) {
                s16x8 a = *(const s16x8*)(lds + AH_OFF + (((m*16 + lr) * 512 + cb) ^ sw));
                acc[m][0] = __builtin_amdgcn_mfma_f32_16x16x32_bf16(a, b[k & 1][0], acc[m][0], 0, 0, 0);
                acc[m][1] = __builtin_amdgcn_mfma_f32_16x16x32_bf16(a, b[k & 1][1], acc[m][1], 0, 0, 0);
                accn[m]   = __builtin_amdgcn_mfma_f32_16x16x32_bf16(a, b[k & 1][2], accn[m],   0, 0, 0);
            }
            if (k < 6) {
                #pragma unroll
                for (int i = 0; i < 3; ++i)
                    b[k & 1][i] = load_b<USE_WS>(W_hh, Wh, w + 16*i, k + 2, MEMH, 8, lane);
            }
        }
    }

    // ---- gate epilogue IN REGISTERS (A_h LDS intact). Lane column j.
    const int j = w * 16 + lr;               // 0..255
    f32x4 o_[4];
    {
        const float br = b_ih[j]       + b_hh[j];
        const float bz = b_ih[256 + j] + b_hh[256 + j];
        const float bihn = b_ih[512 + j], bhhn = b_hh[512 + j];
        #pragma unroll
        for (int m = 0; m < 4; ++m) {
            #pragma unroll
            for (int q = 0; q < 4; ++q) {
                int row = m * 16 + lq * 4 + q;
                float r = sigf(acc[m][0][q] + br);
                float z = sigf(acc[m][1][q] + bz);
                float n = tanh_fast(acc[m][2][q] + bihn + r * (accn[m][q] + bhhn));
                float hv = bf2f(*(const short*)(lds + AH_OFF + ((row * 512 + j * 2) ^ ((row & 7) << 4))));
                o_[m][q] = (1.f - z) * n + z * hv;
            }
        }
    }

    // ---- per-wave LN partials: sum over this wave's 16 cols per row
    {
        float* part = (float*)(lds + PART_OFF);
        #pragma unroll
        for (int m = 0; m < 4; ++m) {
            #pragma unroll
            for (int q = 0; q < 4; ++q) {
                float v = o_[m][q];
                float s1 = v, s2 = v * v;
                #pragma unroll
                for (int mk = 1; mk < 16; mk <<= 1) {
                    s1 += __shfl_xor(s1, mk);
                    s2 += __shfl_xor(s2, mk);
                }
                if (lr == 0) {
                    int row = m * 16 + lq * 4 + q;
                    part[(row * 16 + w) * 2]     = s1;
                    part[(row * 16 + w) * 2 + 1] = s2;
                }
            }
        }
    }
    __syncthreads();

    // ---- stage-2: wave w reduces rows 4w..4w+3 (lane group lq -> one row)
    {
        const float* part = (const float*)(lds + PART_OFF);
        int row = w * 4 + lq;
        float s1 = part[(row * 16 + lr) * 2];
        float s2 = part[(row * 16 + lr) * 2 + 1];
        #pragma unroll
        for (int mk = 1; mk < 16; mk <<= 1) {
            s1 += __shfl_xor(s1, mk);
            s2 += __shfl_xor(s2, mk);
        }
        if (lr == 0) {
            float mu  = s1 * (1.f / 256.f);
            float var = fmaxf(s2 * (1.f / 256.f) - mu * mu, 0.f);
            float* st = (float*)(lds + STAT_OFF);
            st[row * 2]     = mu;
            st[row * 2 + 1] = rsqrtf(var + 1e-5f);
        }
    }
    __syncthreads();

    // ---- normalize + scatter
    {
        const float* st = (const float*)(lds + STAT_OFF);
        const float ga = gamma[j], be = beta[j];
        #pragma unroll
        for (int m = 0; m < 4; ++m) {
            #pragma unroll
            for (int q = 0; q < 4; ++q) {
                int row = m * 16 + lq * 4 + q;
                float mu  = st[row * 2];
                float inv = st[row * 2 + 1];
                int id = ids[base + row];
                float y = (o_[m][q] - mu) * inv * ga + be;
                __builtin_nontemporal_store(y, out_mem + (size_t)id * MEMH + j);
            }
        }
        if (w == 0) {
            int id = ids[base + lane];
            __builtin_nontemporal_store(ts[base + lane], out_lu + id);
        }
    }
}

// ------------------------------------------------------------------- launcher
extern "C" void kernel_launch(void* const* d_in, const int* in_sizes, int n_in,
                              void* d_out, int out_size, void* d_ws, size_t ws_size,
                              hipStream_t stream) {
    (void)n_in; (void)out_size;
    const int*   ids = (const int*)  d_in[0];
    const float* msg = (const float*)d_in[1];
    const float* ts  = (const float*)d_in[2];
    const float* mem = (const float*)d_in[3];
    const float* lu  = (const float*)d_in[4];
    const float* Wih = (const float*)d_in[5];
    const float* Whh = (const float*)d_in[6];
    const float* bih = (const float*)d_in[7];
    const float* bhh = (const float*)d_in[8];
    const float* gam = (const float*)d_in[9];
    const float* bet = (const float*)d_in[10];

    const int  n_upd   = in_sizes[0];                 // 65536
    const long n_nodes = (long)in_sizes[3] / MEMH;    // 500000

    float* out_mem = (float*)d_out;
    float* out_lu  = out_mem + (size_t)n_nodes * MEMH;

    const int    bm_words     = (int)((n_nodes + 31) / 32) + 4;   // padded
    const size_t bm_bytes_pad = (size_t)bm_words * 4;
    const bool ws_w  = (d_ws != nullptr) && (ws_size >= W_BYTES);
    const bool ws_bm = (d_ws != nullptr) && (ws_size >= W_BYTES + bm_bytes_pad);

    short*    wsw = (short*)d_ws;
    unsigned* bm  = (unsigned*)((char*)d_ws + W_BYTES);

    const int grid = n_upd / BM;   // 65536/64 = 1024

    if (ws_w) {
        smu_cvtw_kernel<<<(W_TOT_ELEMS + 255) / 256, 256, 0, stream>>>(Wih, Whh, wsw);
    }

    if (ws_bm) {
        smu_clear_kernel<<<(bm_words + 255) / 256, 256, 0, stream>>>(bm, bm_words);
        smu_bits_kernel<<<(n_upd + 255) / 256, 256, 0, stream>>>(ids, bm, n_upd);
        // single fused dispatch: even blocks GRU, odd blocks bitmap-skipped copy
        smu_fused_kernel<true, true><<<2 * grid, NTHR, 0, stream>>>(
            ids, msg, ts, mem, lu, Wih, Whh, bih, bhh, gam, bet,
            wsw, bm, out_mem, out_lu, n_nodes);
    } else {
        // fallback: full copy first, then GRU scatter overwrites updated rows
        long n_mem4 = n_nodes * (MEMH / 4);
        long n_lu4  = n_nodes / 4;
        smu_copy_kernel<<<2048, 256, 0, stream>>>(mem, lu, out_mem, out_lu, n_mem4, n_lu4);
        if (ws_w) {
            smu_fused_kernel<true, false><<<grid, NTHR, 0, stream>>>(
                ids, msg, ts, mem, lu, Wih, Whh, bih, bhh, gam, bet,
                wsw, nullptr, out_mem, out_lu, n_nodes);
        } else {
            smu_fused_kernel<false, false><<<grid, NTHR, 0, stream>>>(
                ids, msg, ts, mem, lu, Wih, Whh, bih, bhh, gam, bet,
                nullptr, nullptr, out_mem, out_lu, n_nodes);
        }
    }
}

// Round 14
// 327.748 us; speedup vs baseline: 1.1333x; 1.0345x over previous
//
#include <hip/hip_runtime.h>
#include <hip/hip_bf16.h>

typedef float  f32x4 __attribute__((ext_vector_type(4)));
typedef short  s16x8 __attribute__((ext_vector_type(8)));

#define MEMH   256        // mem_dim
#define MSGD   512        // msg_dim
#define G3     768        // 3*H
#define W_IH_ELEMS (G3*MSGD)        // 393216
#define W_HH_ELEMS (G3*MEMH)        // 196608
#define W_TOT_ELEMS (W_IH_ELEMS + W_HH_ELEMS)  // 589824
#define W_BYTES    ((size_t)W_TOT_ELEMS * 2)   // 1179648

#define BM     64         // rows per GRU block
#define NTHR   1024       // 16 waves
#define AH_OFF 0          // A_h: 64x256 bf16, pitch 512 B  -> 32768 B
#define AM_OFF 32768      // A_msg: 64x512 bf16, pitch 1024 B -> 65536 B
#define O_OFF  32768      // O fp32 64x260 (pitch 1040 B) reuses A_msg region
#define LDS_BYTES (32768 + 66560)   // 99328

static __device__ __forceinline__ short f2bf(float x) {
    __hip_bfloat16 b = __float2bfloat16(x);
    return __builtin_bit_cast(short, b);
}
static __device__ __forceinline__ float bf2f(short s) {
    unsigned int u = ((unsigned int)(unsigned short)s) << 16;
    return __builtin_bit_cast(float, u);
}
static __device__ __forceinline__ float sigf(float x) {
    return 1.f / (1.f + __expf(-x));
}
static __device__ __forceinline__ float tanh_fast(float x) {
    float e = __expf(-2.f * fabsf(x));
    float t = (1.f - e) / (1.f + e);
    return copysignf(t, x);
}
static __device__ __forceinline__ f32x4 ntload4(const float* p) {
    return __builtin_nontemporal_load((const f32x4*)p);
}
static __device__ __forceinline__ void ntstore4(float* p, f32x4 v) {
    __builtin_nontemporal_store(v, (f32x4*)p);
}

// ------------------------------------------------- full copy kernel (fallback)
__global__ void smu_copy_kernel(const float* __restrict__ mem,
                                const float* __restrict__ lu,
                                float* __restrict__ out_mem,
                                float* __restrict__ out_lu,
                                long n_mem4, long n_lu4) {
    long i = (long)blockIdx.x * blockDim.x + threadIdx.x;
    long stride = (long)gridDim.x * blockDim.x;
    long total = n_mem4 + n_lu4;
    for (; i < total; i += stride) {
        if (i < n_mem4) ntstore4(out_mem + i * 4, ntload4(mem + i * 4));
        else {
            long j = (i - n_mem4) * 4;
            ntstore4(out_lu + j, ntload4(lu + j));
        }
    }
}

// --------------------------------------------------- weight fp32->bf16 PACKED fragment layout
// ih: frag (t in [0,48), k in [0,16)) at elem off (t*16+k)*512; within frag
// elem idx = l*8+e  ->  source row t*16+(l&15), col k*32+(l>>4)*8+e.
// hh: frag (t in [0,48), k in [0,8)) at W_IH_ELEMS + (t*8+k)*512, same inner map.
__global__ void smu_cvtw_kernel(const float* __restrict__ wih,
                                const float* __restrict__ whh,
                                short* __restrict__ o) {
    int i = blockIdx.x * blockDim.x + threadIdx.x;
    if (i >= W_TOT_ELEMS) return;
    if (i < W_IH_ELEMS) {
        int f = i >> 9, r = i & 511, l = r >> 3, e = r & 7;
        int t = f >> 4, k = f & 15;
        int row = t * 16 + (l & 15), col = k * 32 + (l >> 4) * 8 + e;
        o[i] = f2bf(wih[row * MSGD + col]);
    } else {
        int j = i - W_IH_ELEMS;
        int f = j >> 9, r = j & 511, l = r >> 3, e = r & 7;
        int t = f >> 3, k = f & 7;
        int row = t * 16 + (l & 15), col = k * 32 + (l >> 4) * 8 + e;
        o[i] = f2bf(whh[row * MEMH + col]);
    }
}

// --------------------------------------------------- bitmap clear + set
__global__ void smu_clear_kernel(unsigned* __restrict__ p, int n) {
    int i = blockIdx.x * blockDim.x + threadIdx.x;
    if (i < n) p[i] = 0u;
}
__global__ void smu_bits_kernel(const int* __restrict__ ids,
                                unsigned* __restrict__ bm, int n) {
    int i = blockIdx.x * blockDim.x + threadIdx.x;
    if (i < n) {
        int id = ids[i];
        atomicOr(&bm[id >> 5], 1u << (id & 31));
    }
}

// ------------------------------------------------------------ B-frag loader
// packed path: one contiguous 1KB wave load. fallback: scattered f32 converts.
template<bool USE_WS>
static __device__ __forceinline__ s16x8 load_b(const float* __restrict__ Wf,
                                               const short* __restrict__ Wb,
                                               int t, int k, int ldk, int nkt, int lane) {
    if constexpr (USE_WS) {
        return *(const s16x8*)(Wb + ((size_t)(t * nkt + k) << 9) + lane * 8);
    } else {
        int row = t * 16 + (lane & 15);
        int col = k * 32 + (lane >> 4) * 8;
        f32x4 x = *(const f32x4*)(Wf + (size_t)row * ldk + col);
        f32x4 y = *(const f32x4*)(Wf + (size_t)row * ldk + col + 4);
        s16x8 s;
        s[0]=f2bf(x[0]); s[1]=f2bf(x[1]); s[2]=f2bf(x[2]); s[3]=f2bf(x[3]);
        s[4]=f2bf(y[0]); s[5]=f2bf(y[1]); s[6]=f2bf(y[2]); s[7]=f2bf(y[3]);
        return s;
    }
}

// --------------------------------------------------------------- fused kernel
// grid = 2*n_gru_blocks. Even blocks: GRU+LN (BM=64 rows each). Odd blocks:
// bitmap-skipped copy of memory/last_update. Whole-block role divergence;
// row ownership disjoint (bitmap) -> race-free in any execution order.
// This is the round-7 kernel verbatim — the best measured configuration
// (326.8 us total). Rounds 8-13 tried co-resident roles, wave-split roles,
// de-fusion, pipelined staging, per-wave DMA, and a register epilogue; all
// measured worse (339-378). Consolidation round: ship the best.
template<bool USE_WS>
__global__ __launch_bounds__(NTHR, 1)
void smu_fused_kernel(const int*   __restrict__ ids,
                      const float* __restrict__ msg,
                      const float* __restrict__ ts,
                      const float* __restrict__ memory,
                      const float* __restrict__ lu,
                      const float* __restrict__ W_ih,
                      const float* __restrict__ W_hh,
                      const float* __restrict__ b_ih,
                      const float* __restrict__ b_hh,
                      const float* __restrict__ gamma,
                      const float* __restrict__ beta,
                      const short* __restrict__ wsw,
                      const unsigned* __restrict__ bm,
                      float* __restrict__ out_mem,
                      float* __restrict__ out_lu,
                      long n_nodes) {
    __shared__ __align__(16) unsigned char lds[LDS_BYTES];
    const int tid = threadIdx.x;
    const int bid = blockIdx.x;

    if (bid & 1) {
        // ================= COPY role =================
        const long nblk   = gridDim.x >> 1;
        const long cid    = bid >> 1;
        const long nu     = n_nodes * (MEMH / 4);           // 16B units
        const long stride = nblk * NTHR;
        const long i0     = cid * NTHR + tid;

        for (long i = i0; i < nu; i += stride * 4) {
            long  u0 = i, u1 = i + stride, u2 = i + stride * 2, u3 = i + stride * 3;
            f32x4 v0, v1, v2, v3;
            bool  f0 = false, f1 = false, f2 = false, f3 = false;
            {
                long r0 = u0 >> 6;
                f0 = !((bm[r0 >> 5] >> (r0 & 31)) & 1u);
                if (f0) v0 = ntload4(memory + u0 * 4);
            }
            if (u1 < nu) {
                long r1 = u1 >> 6;
                f1 = !((bm[r1 >> 5] >> (r1 & 31)) & 1u);
                if (f1) v1 = ntload4(memory + u1 * 4);
            }
            if (u2 < nu) {
                long r2 = u2 >> 6;
                f2 = !((bm[r2 >> 5] >> (r2 & 31)) & 1u);
                if (f2) v2 = ntload4(memory + u2 * 4);
            }
            if (u3 < nu) {
                long r3 = u3 >> 6;
                f3 = !((bm[r3 >> 5] >> (r3 & 31)) & 1u);
                if (f3) v3 = ntload4(memory + u3 * 4);
            }
            if (f0) ntstore4(out_mem + u0 * 4, v0);
            if (f1) ntstore4(out_mem + u1 * 4, v1);
            if (f2) ntstore4(out_mem + u2 * 4, v2);
            if (f3) ntstore4(out_mem + u3 * 4, v3);
        }
        // last_update (2 MB): scalar, bitmap-guarded
        for (long i = i0; i < n_nodes; i += stride) {
            if (!((bm[i >> 5] >> (i & 31)) & 1u)) {
                float v = __builtin_nontemporal_load(lu + i);
                __builtin_nontemporal_store(v, out_lu + i);
            }
        }
        return;
    }

    // ================= GRU role =================
    const long base = (long)(bid >> 1) * BM;

    // ---- stage A_msg: 64x512 f32 -> bf16 (4096 8-elem units, 4/thread)
    {
        const float* src = msg + base * MSGD;
        #pragma unroll
        for (int it = 0; it < 4; ++it) {
            int u = tid + NTHR * it;         // 0..4095
            int row = u >> 6;                // 64 units per row
            f32x4 a = ntload4(src + u * 8);
            f32x4 b = ntload4(src + u * 8 + 4);
            s16x8 s;
            s[0]=f2bf(a[0]); s[1]=f2bf(a[1]); s[2]=f2bf(a[2]); s[3]=f2bf(a[3]);
            s[4]=f2bf(b[0]); s[5]=f2bf(b[1]); s[6]=f2bf(b[2]); s[7]=f2bf(b[3]);
            int byte = AM_OFF + ((u * 16) ^ ((row & 7) << 4));
            *(s16x8*)(lds + byte) = s;
        }
        // ---- stage A_h (gather): 64x256 (2048 units, 2/thread)
        #pragma unroll
        for (int it = 0; it < 2; ++it) {
            int u = tid + NTHR * it;         // 0..2047
            int row = u >> 5;                // 32 units per row
            int c8  = u & 31;
            int id  = ids[base + row];
            const float* hs = memory + (size_t)id * MEMH + c8 * 8;
            f32x4 a = ntload4(hs);
            f32x4 b = ntload4(hs + 4);
            s16x8 s;
            s[0]=f2bf(a[0]); s[1]=f2bf(a[1]); s[2]=f2bf(a[2]); s[3]=f2bf(a[3]);
            s[4]=f2bf(b[0]); s[5]=f2bf(b[1]); s[6]=f2bf(b[2]); s[7]=f2bf(b[3]);
            int byte = AH_OFF + ((u * 16) ^ ((row & 7) << 4));
            *(s16x8*)(lds + byte) = s;
        }
    }
    __syncthreads();

    const int lane = tid & 63;
    const int w    = tid >> 6;              // 0..15
    const int lr   = lane & 15;
    const int lk8  = (lane >> 4) * 8;       // k offset within 32-wide ktile
    const int sw   = (lr & 7) << 4;
    const short* Wi = wsw;
    const short* Wh = wsw + W_IH_ELEMS;

    f32x4 acc[4][3] = {};   // [m][0]=r-sum  [1]=z-sum  [2]=gi_n
    f32x4 accn[4]   = {};   // gh_n

    // ---- GEMM 1: gi += msg @ W_ih^T  (K=512, 16 ktiles, depth-2 B prefetch)
    {
        s16x8 b[2][3];
        #pragma unroll
        for (int i = 0; i < 3; ++i) b[0][i] = load_b<USE_WS>(W_ih, Wi, w + 16*i, 0, MSGD, 16, lane);
        #pragma unroll
        for (int i = 0; i < 3; ++i) b[1][i] = load_b<USE_WS>(W_ih, Wi, w + 16*i, 1, MSGD, 16, lane);
        #pragma unroll
        for (int k = 0; k < 16; ++k) {
            const int cb = (k * 32 + lk8) * 2;
            #pragma unroll
            for (int m = 0; m < 4; ++m) {
                s16x8 a = *(const s16x8*)(lds + AM_OFF + (((m*16 + lr) * 1024 + cb) ^ sw));
                #pragma unroll
                for (int i = 0; i < 3; ++i)
                    acc[m][i] = __builtin_amdgcn_mfma_f32_16x16x32_bf16(a, b[k & 1][i], acc[m][i], 0, 0, 0);
            }
            if (k < 14) {
                #pragma unroll
                for (int i = 0; i < 3; ++i)
                    b[k & 1][i] = load_b<USE_WS>(W_ih, Wi, w + 16*i, k + 2, MSGD, 16, lane);
            }
        }
    }
    // ---- GEMM 2: h @ W_hh^T  (K=256, 8 ktiles)
    {
        s16x8 b[2][3];
        #pragma unroll
        for (int i = 0; i < 3; ++i) b[0][i] = load_b<USE_WS>(W_hh, Wh, w + 16*i, 0, MEMH, 8, lane);
        #pragma unroll
        for (int i = 0; i < 3; ++i) b[1][i] = load_b<USE_WS>(W_hh, Wh, w + 16*i, 1, MEMH, 8, lane);
        #pragma unroll
        for (int k = 0; k < 8; ++k) {
            const int cb = (k * 32 + lk8) * 2;
            #pragma unroll
            for (int m = 0; m < 4; ++m) {
                s16x8 a = *(const s16x8*)(lds + AH_OFF + (((m*16 + lr) * 512 + cb) ^ sw));
                acc[m][0] = __builtin_amdgcn_mfma_f32_16x16x32_bf16(a, b[k & 1][0], acc[m][0], 0, 0, 0);
                acc[m][1] = __builtin_amdgcn_mfma_f32_16x16x32_bf16(a, b[k & 1][1], acc[m][1], 0, 0, 0);
                accn[m]   = __builtin_amdgcn_mfma_f32_16x16x32_bf16(a, b[k & 1][2], accn[m],   0, 0, 0);
            }
            if (k < 6) {
                #pragma unroll
                for (int i = 0; i < 3; ++i)
                    b[k & 1][i] = load_b<USE_WS>(W_hh, Wh, w + 16*i, k + 2, MEMH, 8, lane);
            }
        }
    }

    __syncthreads();   // all A_msg reads done before O overwrites region

    // ---- gate epilogue: C layout col=lane&15, row=(lane>>4)*4+q
    {
        const int lq = (lane >> 4) * 4;
        const int j  = w * 16 + lr;          // this lane's output column
        const float br = b_ih[j]       + b_hh[j];
        const float bz = b_ih[256 + j] + b_hh[256 + j];
        const float bihn = b_ih[512 + j], bhhn = b_hh[512 + j];
        #pragma unroll
        for (int m = 0; m < 4; ++m) {
            #pragma unroll
            for (int q = 0; q < 4; ++q) {
                int row = m * 16 + lq + q;
                float r = sigf(acc[m][0][q] + br);
                float z = sigf(acc[m][1][q] + bz);
                float n = tanh_fast(acc[m][2][q] + bihn + r * (accn[m][q] + bhhn));
                float hv = bf2f(*(const short*)(lds + AH_OFF + ((row * 512 + j * 2) ^ ((row & 7) << 4))));
                float o = (1.f - z) * n + z * hv;
                *(float*)(lds + O_OFF + (row * 260 + j) * 4) = o;
            }
        }
    }
    __syncthreads();

    // ---- LayerNorm + scatter: wave w handles rows 4w..4w+3
    #pragma unroll
    for (int rr = 0; rr < 4; ++rr) {
        int row = w * 4 + rr;
        f32x4 x = *(const f32x4*)(lds + O_OFF + (row * 260 + lane * 4) * 4);
        float s1 = x[0] + x[1] + x[2] + x[3];
        float s2 = x[0]*x[0] + x[1]*x[1] + x[2]*x[2] + x[3]*x[3];
        #pragma unroll
        for (int mm = 32; mm > 0; mm >>= 1) {
            s1 += __shfl_xor(s1, mm);
            s2 += __shfl_xor(s2, mm);
        }
        float mu  = s1 * (1.f / 256.f);
        float var = fmaxf(s2 * (1.f / 256.f) - mu * mu, 0.f);
        float inv = rsqrtf(var + 1e-5f);
        f32x4 g  = *(const f32x4*)(gamma + lane * 4);
        f32x4 be = *(const f32x4*)(beta  + lane * 4);
        int id = ids[base + row];
        f32x4 y;
        #pragma unroll
        for (int c = 0; c < 4; ++c) y[c] = (x[c] - mu) * inv * g[c] + be[c];
        ntstore4(out_mem + (size_t)id * MEMH + lane * 4, y);
        if (lane == 0) __builtin_nontemporal_store(ts[base + row], out_lu + id);
    }
}

// --------------------------------------------------------------- GRU-only (fallback)
template<bool USE_WS>
__global__ __launch_bounds__(NTHR, 1)
void smu_gru_kernel(const int*   __restrict__ ids,
                    const float* __restrict__ msg,
                    const float* __restrict__ ts,
                    const float* __restrict__ memory,
                    const float* __restrict__ W_ih,
                    const float* __restrict__ W_hh,
                    const float* __restrict__ b_ih,
                    const float* __restrict__ b_hh,
                    const float* __restrict__ gamma,
                    const float* __restrict__ beta,
                    const short* __restrict__ wsw,
                    float* __restrict__ out_mem,
                    float* __restrict__ out_lu) {
    __shared__ __align__(16) unsigned char lds[LDS_BYTES];
    const int tid = threadIdx.x;
    const long base = (long)blockIdx.x * BM;

    {
        const float* src = msg + base * MSGD;
        #pragma unroll
        for (int it = 0; it < 4; ++it) {
            int u = tid + NTHR * it;
            int row = u >> 6;
            f32x4 a = ntload4(src + u * 8);
            f32x4 b = ntload4(src + u * 8 + 4);
            s16x8 s;
            s[0]=f2bf(a[0]); s[1]=f2bf(a[1]); s[2]=f2bf(a[2]); s[3]=f2bf(a[3]);
            s[4]=f2bf(b[0]); s[5]=f2bf(b[1]); s[6]=f2bf(b[2]); s[7]=f2bf(b[3]);
            int byte = AM_OFF + ((u * 16) ^ ((row & 7) << 4));
            *(s16x8*)(lds + byte) = s;
        }
        #pragma unroll
        for (int it = 0; it < 2; ++it) {
            int u = tid + NTHR * it;
            int row = u >> 5;
            int c8  = u & 31;
            int id  = ids[base + row];
            const float* hs = memory + (size_t)id * MEMH + c8 * 8;
            f32x4 a = ntload4(hs);
            f32x4 b = ntload4(hs + 4);
            s16x8 s;
            s[0]=f2bf(a[0]); s[1]=f2bf(a[1]); s[2]=f2bf(a[2]); s[3]=f2bf(a[3]);
            s[4]=f2bf(b[0]); s[5]=f2bf(b[1]); s[6]=f2bf(b[2]); s[7]=f2bf(b[3]);
            int byte = AH_OFF + ((u * 16) ^ ((row & 7) << 4));
            *(s16x8*)(lds + byte) = s;
        }
    }
    __syncthreads();

    const int lane = tid & 63;
    const int w    = tid >> 6;
    const int lr   = lane & 15;
    const int lk8  = (lane >> 4) * 8;
    const int sw   = (lr & 7) << 4;
    const short* Wi = wsw;
    const short* Wh = wsw + W_IH_ELEMS;

    f32x4 acc[4][3] = {};
    f32x4 accn[4]   = {};

    {
        s16x8 b[2][3];
        #pragma unroll
        for (int i = 0; i < 3; ++i) b[0][i] = load_b<USE_WS>(W_ih, Wi, w + 16*i, 0, MSGD, 16, lane);
        #pragma unroll
        for (int i = 0; i < 3; ++i) b[1][i] = load_b<USE_WS>(W_ih, Wi, w + 16*i, 1, MSGD, 16, lane);
        #pragma unroll
        for (int k = 0; k < 16; ++k) {
            const int cb = (k * 32 + lk8) * 2;
            #pragma unroll
            for (int m = 0; m < 4; ++m) {
                s16x8 a = *(const s16x8*)(lds + AM_OFF + (((m*16 + lr) * 1024 + cb) ^ sw));
                #pragma unroll
                for (int i = 0; i < 3; ++i)
                    acc[m][i] = __builtin_amdgcn_mfma_f32_16x16x32_bf16(a, b[k & 1][i], acc[m][i], 0, 0, 0);
            }
            if (k < 14) {
                #pragma unroll
                for (int i = 0; i < 3; ++i)
                    b[k & 1][i] = load_b<USE_WS>(W_ih, Wi, w + 16*i, k + 2, MSGD, 16, lane);
            }
        }
    }
    {
        s16x8 b[2][3];
        #pragma unroll
        for (int i = 0; i < 3; ++i) b[0][i] = load_b<USE_WS>(W_hh, Wh, w + 16*i, 0, MEMH, 8, lane);
        #pragma unroll
        for (int i = 0; i < 3; ++i) b[1][i] = load_b<USE_WS>(W_hh, Wh, w + 16*i, 1, MEMH, 8, lane);
        #pragma unroll
        for (int k = 0; k < 8; ++k) {
            const int cb = (k * 32 + lk8) * 2;
            #pragma unroll
            for (int m = 0; m < 4; ++m) {
                s16x8 a = *(const s16x8*)(lds + AH_OFF + (((m*16 + lr) * 512 + cb) ^ sw));
                acc[m][0] = __builtin_amdgcn_mfma_f32_16x16x32_bf16(a, b[k & 1][0], acc[m][0], 0, 0, 0);
                acc[m][1] = __builtin_amdgcn_mfma_f32_16x16x32_bf16(a, b[k & 1][1], acc[m][1], 0, 0, 0);
                accn[m]   = __builtin_amdgcn_mfma_f32_16x16x32_bf16(a, b[k & 1][2], accn[m],   0, 0, 0);
            }
            if (k < 6) {
                #pragma unroll
                for (int i = 0; i < 3; ++i)
                    b[k & 1][i] = load_b<USE_WS>(W_hh, Wh, w + 16*i, k + 2, MEMH, 8, lane);
            }
        }
    }

    __syncthreads();

    {
        const int lq = (lane >> 4) * 4;
        const int j  = w * 16 + lr;
        const float br = b_ih[j]       + b_hh[j];
        const float bz = b_ih[256 + j] + b_hh[256 + j];
        const float bihn = b_ih[512 + j], bhhn = b_hh[512 + j];
        #pragma unroll
        for (int m = 0; m < 4; ++m) {
            #pragma unroll
            for (int q = 0; q < 4; ++q) {
                int row = m * 16 + lq + q;
                float r = sigf(acc[m][0][q] + br);
                float z = sigf(acc[m][1][q] + bz);
                float n = tanh_fast(acc[m][2][q] + bihn + r * (accn[m][q] + bhhn));
                float hv = bf2f(*(const short*)(lds + AH_OFF + ((row * 512 + j * 2) ^ ((row & 7) << 4))));
                float o = (1.f - z) * n + z * hv;
                *(float*)(lds + O_OFF + (row * 260 + j) * 4) = o;
            }
        }
    }
    __syncthreads();

    #pragma unroll
    for (int rr = 0; rr < 4; ++rr) {
        int row = w * 4 + rr;
        f32x4 x = *(const f32x4*)(lds + O_OFF + (row * 260 + lane * 4) * 4);
        float s1 = x[0] + x[1] + x[2] + x[3];
        float s2 = x[0]*x[0] + x[1]*x[1] + x[2]*x[2] + x[3]*x[3];
        #pragma unroll
        for (int mm = 32; mm > 0; mm >>= 1) {
            s1 += __shfl_xor(s1, mm);
            s2 += __shfl_xor(s2, mm);
        }
        float mu  = s1 * (1.f / 256.f);
        float var = fmaxf(s2 * (1.f / 256.f) - mu * mu, 0.f);
        float inv = rsqrtf(var + 1e-5f);
        f32x4 g  = *(const f32x4*)(gamma + lane * 4);
        f32x4 be = *(const f32x4*)(beta  + lane * 4);
        int id = ids[base + row];
        f32x4 y;
        #pragma unroll
        for (int c = 0; c < 4; ++c) y[c] = (x[c] - mu) * inv * g[c] + be[c];
        ntstore4(out_mem + (size_t)id * MEMH + lane * 4, y);
        if (lane == 0) __builtin_nontemporal_store(ts[base + row], out_lu + id);
    }
}

// ------------------------------------------------------------------- launcher
extern "C" void kernel_launch(void* const* d_in, const int* in_sizes, int n_in,
                              void* d_out, int out_size, void* d_ws, size_t ws_size,
                              hipStream_t stream) {
    (void)n_in; (void)out_size;
    const int*   ids = (const int*)  d_in[0];
    const float* msg = (const float*)d_in[1];
    const float* ts  = (const float*)d_in[2];
    const float* mem = (const float*)d_in[3];
    const float* lu  = (const float*)d_in[4];
    const float* Wih = (const float*)d_in[5];
    const float* Whh = (const float*)d_in[6];
    const float* bih = (const float*)d_in[7];
    const float* bhh = (const float*)d_in[8];
    const float* gam = (const float*)d_in[9];
    const float* bet = (const float*)d_in[10];

    const int  n_upd   = in_sizes[0];                 // 65536
    const long n_nodes = (long)in_sizes[3] / MEMH;    // 500000

    float* out_mem = (float*)d_out;
    float* out_lu  = out_mem + (size_t)n_nodes * MEMH;

    const int    bm_words     = (int)((n_nodes + 31) / 32) + 4;   // padded
    const size_t bm_bytes_pad = (size_t)bm_words * 4;
    const bool ws_w  = (d_ws != nullptr) && (ws_size >= W_BYTES);
    const bool ws_bm = (d_ws != nullptr) && (ws_size >= W_BYTES + bm_bytes_pad);

    short*    wsw = (short*)d_ws;
    unsigned* bm  = (unsigned*)((char*)d_ws + W_BYTES);

    const int grid = n_upd / BM;   // 65536/64 = 1024

    if (ws_w) {
        smu_cvtw_kernel<<<(W_TOT_ELEMS + 255) / 256, 256, 0, stream>>>(Wih, Whh, wsw);
    }

    if (ws_bm) {
        smu_clear_kernel<<<(bm_words + 255) / 256, 256, 0, stream>>>(bm, bm_words);
        smu_bits_kernel<<<(n_upd + 255) / 256, 256, 0, stream>>>(ids, bm, n_upd);
        // single fused dispatch: even blocks GRU, odd blocks bitmap-skipped copy
        smu_fused_kernel<true><<<2 * grid, NTHR, 0, stream>>>(
            ids, msg, ts, mem, lu, Wih, Whh, bih, bhh, gam, bet,
            wsw, bm, out_mem, out_lu, n_nodes);
    } else {
        // fallback: full copy first, then GRU scatter overwrites updated rows
        long n_mem4 = n_nodes * (MEMH / 4);
        long n_lu4  = n_nodes / 4;
        smu_copy_kernel<<<2048, 256, 0, stream>>>(mem, lu, out_mem, out_lu, n_mem4, n_lu4);
        if (ws_w) {
            smu_gru_kernel<true><<<grid, NTHR, 0, stream>>>(
                ids, msg, ts, mem, Wih, Whh, bih, bhh, gam, bet, wsw, out_mem, out_lu);
        } else {
            smu_gru_kernel<false><<<grid, NTHR, 0, stream>>>(
                ids, msg, ts, mem, Wih, Whh, bih, bhh, gam, bet, nullptr, out_mem, out_lu);
        }
    }
}